// Round 3
// baseline (432.001 us; speedup 1.0000x reference)
//
#include <hip/hip_runtime.h>
#include <hip/hip_bf16.h>
#include <math.h>

#define Bn 64
#define Sn 512
#define Hn 1024
#define Tn 48

#define LOG2E 1.4426950408889634f
#define LN2f  0.6931471805599453f

#define PRED_OFF (Bn*Sn*Tn)
#define LOSS_OFF (PRED_OFF + Bn*Sn)

#define RL(x,i) __int_as_float(__builtin_amdgcn_readlane(__float_as_int(x),(i)))

#if __has_builtin(__builtin_amdgcn_exp2f)
#define EXP2(x) __builtin_amdgcn_exp2f(x)
#else
#define EXP2(x) exp2f(x)
#endif
#if __has_builtin(__builtin_amdgcn_logf)
#define LOG2(x) __builtin_amdgcn_logf(x)
#else
#define LOG2(x) log2f(x)
#endif

// DPP row-rotate add (reduce within 16-lane row)
template<int CTRL>
__device__ __forceinline__ float dpp_add(float v) {
  return v + __int_as_float(__builtin_amdgcn_update_dpp(
      0, __float_as_int(v), CTRL, 0xf, 0xf, false));
}

// ======================= GEMM: feat = x @ W + b =======================
// k-split design: no LDS, no barriers. 2048 blocks x 256 threads.
// thread = (klane 0..15, cg 0..15). Block owns 16 rows x 48 cols.
// Each thread: 16 rows x 3 cols partial dots over its 4-k slices;
// final reduce across klane via DPP row_ror; row klane written out.
__global__ __launch_bounds__(256) void gemm_feat(
    const float* __restrict__ x, const float* __restrict__ W,
    const float* __restrict__ bias, float* __restrict__ feat)
{
  const int tid = threadIdx.x;
  const int klane = tid & 15;
  const int cg = tid >> 4;          // 0..15
  const int col0 = cg * 3;
  const size_t row0 = (size_t)blockIdx.x * 16;

  float acc[16][3];
  #pragma unroll
  for (int r = 0; r < 16; ++r) { acc[r][0]=0.f; acc[r][1]=0.f; acc[r][2]=0.f; }

  const float* xb = x + row0 * Hn + klane * 4;
  const float* wb = W + (size_t)(klane * 4) * Tn + col0;

  for (int k0 = 0; k0 < Hn; k0 += 64) {
    float w[3][4];
    #pragma unroll
    for (int kk = 0; kk < 4; ++kk) {
      #pragma unroll
      for (int c = 0; c < 3; ++c)
        w[c][kk] = wb[(size_t)(k0 + kk) * Tn + c];
    }
    float4 a[16];
    #pragma unroll
    for (int r = 0; r < 16; ++r)
      a[r] = *reinterpret_cast<const float4*>(&xb[(size_t)r * Hn + k0]);
    #pragma unroll
    for (int r = 0; r < 16; ++r) {
      #pragma unroll
      for (int c = 0; c < 3; ++c) {
        acc[r][c] = fmaf(a[r].x, w[c][0], acc[r][c]);
        acc[r][c] = fmaf(a[r].y, w[c][1], acc[r][c]);
        acc[r][c] = fmaf(a[r].z, w[c][2], acc[r][c]);
        acc[r][c] = fmaf(a[r].w, w[c][3], acc[r][c]);
      }
    }
  }
  // reduce over the 16 klanes (DPP row_ror: 8,4,2,1)
  #pragma unroll
  for (int r = 0; r < 16; ++r) {
    #pragma unroll
    for (int c = 0; c < 3; ++c) {
      float v = acc[r][c];
      v = dpp_add<0x128>(v);
      v = dpp_add<0x124>(v);
      v = dpp_add<0x122>(v);
      v = dpp_add<0x121>(v);
      acc[r][c] = v;
    }
  }
  // thread with klane==r owns row r; select statically
  float o0 = acc[0][0], o1 = acc[0][1], o2 = acc[0][2];
  #pragma unroll
  for (int r = 1; r < 16; ++r) {
    const bool sel = (klane == r);
    o0 = sel ? acc[r][0] : o0;
    o1 = sel ? acc[r][1] : o1;
    o2 = sel ? acc[r][2] : o2;
  }
  float* fo = feat + (row0 + klane) * Tn + col0;
  fo[0] = o0 + bias[col0 + 0];
  fo[1] = o1 + bias[col0 + 1];
  fo[2] = o2 + bias[col0 + 2];
}

// ======================= CRF: 192 single-wave blocks =======================
// role 0: log-partition (linear-space matvec, log2 rebased)
// role 1: Viterbi forward + segment-parallel backtrace
// role 2: gold score
__global__ __launch_bounds__(64, 1) void crf_kernel(
    const float* __restrict__ feat,
    const int* __restrict__ mask,
    const int* __restrict__ labels,
    const float* __restrict__ trans,
    const float* __restrict__ startv,
    const float* __restrict__ endv,
    float* __restrict__ pred_out,
    float* __restrict__ wsLogZ,
    float* __restrict__ wsGold)
{
  __shared__ unsigned char bpL[Sn * 64];     // 32 KB backpointers, stride 64
  __shared__ unsigned char pathL[384 * 64];  // 24 KB segment paths
  __shared__ int EA[8];

  const int role = blockIdx.x >> 6;
  const int b    = blockIdx.x & 63;
  const int lane = threadIdx.x;
  const float* fb = feat + (size_t)b * Sn * Tn;

  // sequence length (mask is a prefix mask)
  int lc = 0;
  #pragma unroll
  for (int it = 0; it < Sn/64; ++it) lc += (mask[(size_t)b*Sn + it*64 + lane] != 0);
  #pragma unroll
  for (int off = 32; off; off >>= 1) lc += __shfl_xor(lc, off);
  const int len = lc;

  const int j = (lane < Tn) ? lane : (Tn - 1);

  if (role == 0) {
    // ---------------- log-partition ----------------
    float Ev[48];
    #pragma unroll
    for (int i = 0; i < 48; ++i) Ev[i] = EXP2(trans[i*Tn + j] * LOG2E); // e^trans
    const float a0 = (startv[j] + fb[j]) * LOG2E;
    float Zref = RL(a0, 0);
    float beta = a0 - Zref;                  // beta[0] == 0
    float em2 = fb[Tn + j] * LOG2E;
    for (int t = 1; t < len; ++t) {
      const int tn = (t + 1 < len) ? (t + 1) : t;
      const float em_nxt = fb[(size_t)tn*Tn + j] * LOG2E;
      const float p = EXP2(beta);
      float s0=0.f, s1=0.f, s2=0.f, s3=0.f;
      #pragma unroll
      for (int i = 0; i < 48; i += 4) {
        s0 = fmaf(RL(p, i+0), Ev[i+0], s0);
        s1 = fmaf(RL(p, i+1), Ev[i+1], s1);
        s2 = fmaf(RL(p, i+2), Ev[i+2], s2);
        s3 = fmaf(RL(p, i+3), Ev[i+3], s3);
      }
      const float dj = LOG2((s0 + s1) + (s2 + s3)) + em2;
      const float d0 = RL(dj, 0);
      Zref += d0;
      beta = dj - d0;
      em2 = em_nxt;
    }
    float fv = (lane < Tn) ? beta + endv[lane] * LOG2E : -INFINITY;
    float m = fv;
    #pragma unroll
    for (int off = 32; off; off >>= 1) m = fmaxf(m, __shfl_xor(m, off));
    float e = (lane < Tn) ? EXP2(fv - m) : 0.f;
    #pragma unroll
    for (int off = 32; off; off >>= 1) e += __shfl_xor(e, off);
    if (lane == 0) wsLogZ[b] = (Zref + m + LOG2(e)) * LN2f;

  } else if (role == 1) {
    // ---------------- Viterbi forward ----------------
    float trv[48];
    #pragma unroll
    for (int i = 0; i < 48; ++i) trv[i] = trans[i*Tn + j];
    float v = startv[j] + fb[j];
    float em_cur = fb[Tn + j];
    for (int t = 1; t < len; ++t) {
      const int tn = (t + 1 < len) ? (t + 1) : t;
      const float em_nxt = fb[(size_t)tn*Tn + j];
      float q[48];
      #pragma unroll
      for (int i = 0; i < 48; ++i) q[i] = RL(v, i) + trv[i];
      // value: fmax3 tree
      float m16[16];
      #pragma unroll
      for (int u = 0; u < 16; ++u)
        m16[u] = fmaxf(fmaxf(q[3*u], q[3*u+1]), q[3*u+2]);
      float n0 = fmaxf(fmaxf(m16[0],m16[1]),m16[2]);
      float n1 = fmaxf(fmaxf(m16[3],m16[4]),m16[5]);
      float n2 = fmaxf(fmaxf(m16[6],m16[7]),m16[8]);
      float n3 = fmaxf(fmaxf(m16[9],m16[10]),m16[11]);
      float n4 = fmaxf(fmaxf(m16[12],m16[13]),m16[14]);
      float n5 = m16[15];
      const float best = fmaxf(fmaxf(fmaxf(n0,n1),fmaxf(n2,n3)), fmaxf(n4,n5));
      // index: descending first-occurrence scan (exact float equality)
      int idx = 47;
      #pragma unroll
      for (int i = 46; i >= 0; --i) idx = (q[i] == best) ? i : idx;
      bpL[t*64 + lane] = (unsigned char)idx;
      v = best + em_cur;
      em_cur = em_nxt;
    }
    // identity backpointers for masked steps
    for (int t = len; t < Sn; ++t) bpL[t*64 + lane] = (unsigned char)lane;

    // final first-occurrence argmax across lanes
    float fv = (lane < Tn) ? v + endv[lane] : -INFINITY;
    int fi = (lane < Tn) ? lane : 64;
    #pragma unroll
    for (int off = 32; off; off >>= 1) {
      const float ov = __shfl_xor(fv, off);
      const int   oi = __shfl_xor(fi, off);
      if (ov > fv || (ov == fv && oi < fi)) { fv = ov; fi = oi; }
    }
    __syncthreads();

    // ---- segment-parallel backtrace: 8 segments x 48 entry tags = 384 jobs,
    //      6 interleaved chains per lane ----
    #define JOB(r) \
      const int id##r  = lane + 64*(r); \
      const int seg##r = id##r & 7;     \
      int cur##r = id##r >> 3;          \
      const int bpb##r = seg##r << 12;  \
      const int pb##r  = id##r << 6;    \
      pathL[pb##r + 63] = (unsigned char)cur##r;
    JOB(0) JOB(1) JOB(2) JOB(3) JOB(4) JOB(5)
    for (int d = 62; d >= 0; --d) {
      const int o = (d + 1) << 6;
      cur0 = bpL[bpb0 + o + cur0]; pathL[pb0 + d] = (unsigned char)cur0;
      cur1 = bpL[bpb1 + o + cur1]; pathL[pb1 + d] = (unsigned char)cur1;
      cur2 = bpL[bpb2 + o + cur2]; pathL[pb2 + d] = (unsigned char)cur2;
      cur3 = bpL[bpb3 + o + cur3]; pathL[pb3 + d] = (unsigned char)cur3;
      cur4 = bpL[bpb4 + o + cur4]; pathL[pb4 + d] = (unsigned char)cur4;
      cur5 = bpL[bpb5 + o + cur5]; pathL[pb5 + d] = (unsigned char)cur5;
    }
    #undef JOB
    __syncthreads();
    // stitch: E[s] = tag at position 64s+63
    if (lane == 0) {
      int Ecur = fi;                       // tag at 511 (identity-propagated)
      EA[7] = Ecur;
      for (int s = 7; s >= 1; --s) {
        const int bottom = pathL[((Ecur << 3) + s) * 64];   // tag at 64s
        Ecur = bpL[(s << 12) + bottom];                     // bp[64s][.] -> tag at 64s-1
        EA[s-1] = Ecur;
      }
    }
    __syncthreads();
    #pragma unroll
    for (int r8 = 0; r8 < 8; ++r8) {
      const int t = r8*64 + lane;
      const int pv = pathL[((EA[r8] << 3) + r8) * 64 + lane];
      pred_out[(size_t)b*Sn + t] = (t < len) ? (float)pv : 0.f;
    }

  } else {
    // ---------------- gold score ----------------
    float g = 0.f;
    #pragma unroll
    for (int it = 0; it < Sn/64; ++it) {
      const int sg = it*64 + lane;
      if (sg < len) {
        const int la = labels[(size_t)b*Sn + sg];
        float e = fb[(size_t)sg*Tn + la];
        if (sg > 0) e += trans[labels[(size_t)b*Sn + sg - 1]*Tn + la];
        g += e;
      }
    }
    #pragma unroll
    for (int off = 32; off; off >>= 1) g += __shfl_xor(g, off);
    if (lane == 0) {
      g += startv[labels[(size_t)b*Sn]] + endv[labels[(size_t)b*Sn + len - 1]];
      wsGold[b] = g;
    }
  }
}

__global__ void loss_reduce(const float* __restrict__ wsLogZ,
                            const float* __restrict__ wsGold,
                            float* __restrict__ out)
{
  const int lane = threadIdx.x;
  float v = wsLogZ[lane] - wsGold[lane];
  #pragma unroll
  for (int off = 32; off; off >>= 1) v += __shfl_xor(v, off);
  if (lane == 0) out[0] = v;
}

extern "C" void kernel_launch(void* const* d_in, const int* in_sizes, int n_in,
                              void* d_out, int out_size, void* d_ws, size_t ws_size,
                              hipStream_t stream) {
  const float* x      = (const float*)d_in[0];
  const int*   mask   = (const int*)  d_in[1];
  const int*   labels = (const int*)  d_in[2];
  const float* W      = (const float*)d_in[3];
  const float* bias   = (const float*)d_in[4];
  const float* trans  = (const float*)d_in[5];
  const float* startv = (const float*)d_in[6];
  const float* endv   = (const float*)d_in[7];

  float* out  = (float*)d_out;
  float* feat = out;                 // output 0: features [B][S][T]
  float* pred = out + PRED_OFF;      // output 1: pred_labels as float [B][S]
  float* loss = out + LOSS_OFF;      // output 2: scalar loss
  float* wsLogZ = (float*)d_ws;
  float* wsGold = wsLogZ + 64;

  gemm_feat<<<(Bn*Sn)/16, 256, 0, stream>>>(x, W, bias, feat);
  crf_kernel<<<192, 64, 0, stream>>>(feat, mask, labels, trans, startv, endv, pred, wsLogZ, wsGold);
  loss_reduce<<<1, 64, 0, stream>>>(wsLogZ, wsGold, loss);
}

// Round 4
// 356.114 us; speedup vs baseline: 1.2131x; 1.2131x over previous
//
#include <hip/hip_runtime.h>
#include <hip/hip_bf16.h>
#include <math.h>

#define Bn 64
#define Sn 512
#define Hn 1024
#define Tn 48

#define LOG2E 1.4426950408889634f
#define LN2f  0.6931471805599453f

#define PRED_OFF (Bn*Sn*Tn)
#define LOSS_OFF (PRED_OFF + Bn*Sn)

#define RL(x,i) __int_as_float(__builtin_amdgcn_readlane(__float_as_int(x),(i)))

#if __has_builtin(__builtin_amdgcn_exp2f)
#define EXP2(x) __builtin_amdgcn_exp2f(x)
#else
#define EXP2(x) exp2f(x)
#endif
#if __has_builtin(__builtin_amdgcn_logf)
#define LOG2(x) __builtin_amdgcn_logf(x)
#else
#define LOG2(x) log2f(x)
#endif

// ======================= GEMM: feat = x @ W + b =======================
// BM=64, BN=48, BK=64. 256 threads; per-thread 2 rows x 6 cols.
// Grid 512 -> 2 blocks/CU (8 waves/CU). Register-prefetch double buffering.
#define DOT4(ACC,A,B) { ACC = fmaf((A).x,(B).x,ACC); ACC = fmaf((A).y,(B).y,ACC); ACC = fmaf((A).z,(B).z,ACC); ACC = fmaf((A).w,(B).w,ACC); }

__global__ __launch_bounds__(256) void gemm_feat(
    const float* __restrict__ x, const float* __restrict__ W,
    const float* __restrict__ bias, float* __restrict__ feat)
{
  __shared__ __align__(16) float xs[64][68];
  __shared__ __align__(16) float wsT[Tn][68];
  const int tid = threadIdx.x;
  const int srow = tid >> 2;        // 0..63 staging row
  const int sqc  = tid & 3;         // 0..3  staging quad-col base
  const int ty = tid >> 3;          // 0..31 -> rows ty*2, ty*2+1
  const int tx = tid & 7;           // 0..7  -> cols tx*6 .. tx*6+5
  const size_t row0 = (size_t)blockIdx.x * 64;

  float4 xreg[4];
  float  wreg[12];
  #pragma unroll
  for (int p = 0; p < 4; ++p)
    xreg[p] = *reinterpret_cast<const float4*>(&x[(row0 + srow)*Hn + (sqc + p*4)*4]);
  #pragma unroll
  for (int i = 0; i < 12; ++i) {
    const int id = tid + i*256; const int kk = id/Tn; const int t = id - kk*Tn;
    wreg[i] = W[(size_t)kk*Tn + t];
  }

  float acc[2][6];
  #pragma unroll
  for (int r = 0; r < 2; ++r)
    #pragma unroll
    for (int c = 0; c < 6; ++c) acc[r][c] = 0.f;

  for (int k0 = 0; k0 < Hn; k0 += 64) {
    #pragma unroll
    for (int p = 0; p < 4; ++p)
      *reinterpret_cast<float4*>(&xs[srow][(sqc + p*4)*4]) = xreg[p];
    #pragma unroll
    for (int i = 0; i < 12; ++i) {
      const int id = tid + i*256; const int kk = id/Tn; const int t = id - kk*Tn;
      wsT[t][kk] = wreg[i];
    }
    __syncthreads();
    if (k0 + 64 < Hn) {
      #pragma unroll
      for (int p = 0; p < 4; ++p)
        xreg[p] = *reinterpret_cast<const float4*>(&x[(row0 + srow)*Hn + (k0+64) + (sqc + p*4)*4]);
      #pragma unroll
      for (int i = 0; i < 12; ++i) {
        const int id = tid + i*256; const int kk = id/Tn; const int t = id - kk*Tn;
        wreg[i] = W[(size_t)(k0 + 64 + kk)*Tn + t];
      }
    }
    #pragma unroll 4
    for (int kk = 0; kk < 64; kk += 4) {
      const float4 a0 = *reinterpret_cast<const float4*>(&xs[ty*2+0][kk]);
      const float4 a1 = *reinterpret_cast<const float4*>(&xs[ty*2+1][kk]);
      const float4 w0 = *reinterpret_cast<const float4*>(&wsT[tx*6+0][kk]);
      const float4 w1 = *reinterpret_cast<const float4*>(&wsT[tx*6+1][kk]);
      const float4 w2 = *reinterpret_cast<const float4*>(&wsT[tx*6+2][kk]);
      const float4 w3 = *reinterpret_cast<const float4*>(&wsT[tx*6+3][kk]);
      const float4 w4 = *reinterpret_cast<const float4*>(&wsT[tx*6+4][kk]);
      const float4 w5 = *reinterpret_cast<const float4*>(&wsT[tx*6+5][kk]);
      DOT4(acc[0][0],a0,w0) DOT4(acc[0][1],a0,w1) DOT4(acc[0][2],a0,w2)
      DOT4(acc[0][3],a0,w3) DOT4(acc[0][4],a0,w4) DOT4(acc[0][5],a0,w5)
      DOT4(acc[1][0],a1,w0) DOT4(acc[1][1],a1,w1) DOT4(acc[1][2],a1,w2)
      DOT4(acc[1][3],a1,w3) DOT4(acc[1][4],a1,w4) DOT4(acc[1][5],a1,w5)
    }
    __syncthreads();
  }
  #pragma unroll
  for (int c = 0; c < 6; ++c) {
    const int col = tx*6 + c;
    const float bv = bias[col];
    #pragma unroll
    for (int r = 0; r < 2; ++r)
      feat[(row0 + ty*2 + r)*Tn + col] = acc[r][c] + bv;
  }
}

// ======================= CRF: 192 single-wave blocks =======================
// role 0: log-partition (linear-space matvec, log2 rebased)
// role 1: Viterbi forward (R2-style group-streaming argmax, low reg pressure)
//         + segment-parallel backtrace
// role 2: gold score
__global__ __launch_bounds__(64, 1) void crf_kernel(
    const float* __restrict__ feat,
    const int* __restrict__ mask,
    const int* __restrict__ labels,
    const float* __restrict__ trans,
    const float* __restrict__ startv,
    const float* __restrict__ endv,
    float* __restrict__ pred_out,
    float* __restrict__ wsLogZ,
    float* __restrict__ wsGold)
{
  __shared__ unsigned char bpL[Sn * 64];     // 32 KB backpointers, stride 64
  __shared__ unsigned char pathL[384 * 64];  // 24 KB segment paths
  __shared__ int EA[8];

  const int role = blockIdx.x >> 6;
  const int b    = blockIdx.x & 63;
  const int lane = threadIdx.x;
  const float* fb = feat + (size_t)b * Sn * Tn;

  // sequence length (mask is a prefix mask)
  int lc = 0;
  #pragma unroll
  for (int it = 0; it < Sn/64; ++it) lc += (mask[(size_t)b*Sn + it*64 + lane] != 0);
  #pragma unroll
  for (int off = 32; off; off >>= 1) lc += __shfl_xor(lc, off);
  const int len = lc;

  const int j = (lane < Tn) ? lane : (Tn - 1);

  if (role == 0) {
    // ---------------- log-partition ----------------
    float Ev[48];
    #pragma unroll
    for (int i = 0; i < 48; ++i) Ev[i] = EXP2(trans[i*Tn + j] * LOG2E); // e^trans
    const float a0 = (startv[j] + fb[j]) * LOG2E;
    float Zref = RL(a0, 0);
    float beta = a0 - Zref;                  // beta[0] == 0
    float em2 = fb[Tn + j] * LOG2E;
    for (int t = 1; t < len; ++t) {
      const int tn = (t + 1 < len) ? (t + 1) : t;
      const float em_nxt = fb[(size_t)tn*Tn + j] * LOG2E;
      const float p = EXP2(beta);
      float s0=0.f, s1=0.f, s2=0.f, s3=0.f;
      #pragma unroll
      for (int i = 0; i < 48; i += 4) {
        s0 = fmaf(RL(p, i+0), Ev[i+0], s0);
        s1 = fmaf(RL(p, i+1), Ev[i+1], s1);
        s2 = fmaf(RL(p, i+2), Ev[i+2], s2);
        s3 = fmaf(RL(p, i+3), Ev[i+3], s3);
      }
      const float dj = LOG2((s0 + s1) + (s2 + s3)) + em2;
      const float d0 = RL(dj, 0);
      Zref += d0;
      beta = dj - d0;
      em2 = em_nxt;
    }
    float fv = (lane < Tn) ? beta + endv[lane] * LOG2E : -INFINITY;
    float m = fv;
    #pragma unroll
    for (int off = 32; off; off >>= 1) m = fmaxf(m, __shfl_xor(m, off));
    float e = (lane < Tn) ? EXP2(fv - m) : 0.f;
    #pragma unroll
    for (int off = 32; off; off >>= 1) e += __shfl_xor(e, off);
    if (lane == 0) wsLogZ[b] = (Zref + m + LOG2(e)) * LN2f;

  } else if (role == 1) {
    // ---------------- Viterbi forward (group-streaming argmax) ----------------
    float trv[48];
    #pragma unroll
    for (int i = 0; i < 48; ++i) trv[i] = trans[i*Tn + j];
    float v = startv[j] + fb[j];
    float em_cur = fb[Tn + j];
    for (int t = 1; t < len; ++t) {
      const int tn = (t + 1 < len) ? (t + 1) : t;
      const float em_nxt = fb[(size_t)tn*Tn + j];
      float bestA = -INFINITY, bestB = -INFINITY;
      int idxA = 0, idxB = 0;
      #pragma unroll
      for (int k = 0; k < 12; ++k) {
        const float q0 = RL(v, 4*k+0) + trv[4*k+0];
        const float q1 = RL(v, 4*k+1) + trv[4*k+1];
        const float q2 = RL(v, 4*k+2) + trv[4*k+2];
        const float q3 = RL(v, 4*k+3) + trv[4*k+3];
        // group first-occurrence argmax (strict > keeps lowest index)
        float gv = q0; int gi = 4*k;
        bool g1 = q1 > gv; gv = g1 ? q1 : gv; gi = g1 ? 4*k+1 : gi;
        bool g2 = q2 > gv; gv = g2 ? q2 : gv; gi = g2 ? 4*k+2 : gi;
        bool g3 = q3 > gv; gv = g3 ? q3 : gv; gi = g3 ? 4*k+3 : gi;
        if ((k & 1) == 0) { bool g = gv > bestA; bestA = g ? gv : bestA; idxA = g ? gi : idxA; }
        else              { bool g = gv > bestB; bestB = g ? gv : bestB; idxB = g ? gi : idxB; }
      }
      float best; int bidx;
      if (bestB > bestA || (bestB == bestA && idxB < idxA)) { best = bestB; bidx = idxB; }
      else                                                  { best = bestA; bidx = idxA; }
      bpL[t*64 + lane] = (unsigned char)bidx;
      v = best + em_cur;
      em_cur = em_nxt;
    }
    // identity backpointers for masked steps
    for (int t = len; t < Sn; ++t) bpL[t*64 + lane] = (unsigned char)lane;

    // final first-occurrence argmax across lanes
    float fv = (lane < Tn) ? v + endv[lane] : -INFINITY;
    int fi = (lane < Tn) ? lane : 64;
    #pragma unroll
    for (int off = 32; off; off >>= 1) {
      const float ov = __shfl_xor(fv, off);
      const int   oi = __shfl_xor(fi, off);
      if (ov > fv || (ov == fv && oi < fi)) { fv = ov; fi = oi; }
    }
    __syncthreads();

    // ---- segment-parallel backtrace: 8 segments x 48 entry tags = 384 jobs,
    //      6 interleaved chains per lane ----
    #define JOB(r) \
      const int id##r  = lane + 64*(r); \
      const int seg##r = id##r & 7;     \
      int cur##r = id##r >> 3;          \
      const int bpb##r = seg##r << 12;  \
      const int pb##r  = id##r << 6;    \
      pathL[pb##r + 63] = (unsigned char)cur##r;
    JOB(0) JOB(1) JOB(2) JOB(3) JOB(4) JOB(5)
    for (int d = 62; d >= 0; --d) {
      const int o = (d + 1) << 6;
      cur0 = bpL[bpb0 + o + cur0]; pathL[pb0 + d] = (unsigned char)cur0;
      cur1 = bpL[bpb1 + o + cur1]; pathL[pb1 + d] = (unsigned char)cur1;
      cur2 = bpL[bpb2 + o + cur2]; pathL[pb2 + d] = (unsigned char)cur2;
      cur3 = bpL[bpb3 + o + cur3]; pathL[pb3 + d] = (unsigned char)cur3;
      cur4 = bpL[bpb4 + o + cur4]; pathL[pb4 + d] = (unsigned char)cur4;
      cur5 = bpL[bpb5 + o + cur5]; pathL[pb5 + d] = (unsigned char)cur5;
    }
    #undef JOB
    __syncthreads();
    // stitch: E[s] = tag at position 64s+63
    if (lane == 0) {
      int Ecur = fi;                       // tag at 511 (identity-propagated)
      EA[7] = Ecur;
      for (int s = 7; s >= 1; --s) {
        const int bottom = pathL[((Ecur << 3) + s) * 64];   // tag at 64s
        Ecur = bpL[(s << 12) + bottom];                     // bp[64s][.] -> tag at 64s-1
        EA[s-1] = Ecur;
      }
    }
    __syncthreads();
    #pragma unroll
    for (int r8 = 0; r8 < 8; ++r8) {
      const int t = r8*64 + lane;
      const int pv = pathL[((EA[r8] << 3) + r8) * 64 + lane];
      pred_out[(size_t)b*Sn + t] = (t < len) ? (float)pv : 0.f;
    }

  } else {
    // ---------------- gold score ----------------
    float g = 0.f;
    #pragma unroll
    for (int it = 0; it < Sn/64; ++it) {
      const int sg = it*64 + lane;
      if (sg < len) {
        const int la = labels[(size_t)b*Sn + sg];
        float e = fb[(size_t)sg*Tn + la];
        if (sg > 0) e += trans[labels[(size_t)b*Sn + sg - 1]*Tn + la];
        g += e;
      }
    }
    #pragma unroll
    for (int off = 32; off; off >>= 1) g += __shfl_xor(g, off);
    if (lane == 0) {
      g += startv[labels[(size_t)b*Sn]] + endv[labels[(size_t)b*Sn + len - 1]];
      wsGold[b] = g;
    }
  }
}

__global__ void loss_reduce(const float* __restrict__ wsLogZ,
                            const float* __restrict__ wsGold,
                            float* __restrict__ out)
{
  const int lane = threadIdx.x;
  float v = wsLogZ[lane] - wsGold[lane];
  #pragma unroll
  for (int off = 32; off; off >>= 1) v += __shfl_xor(v, off);
  if (lane == 0) out[0] = v;
}

extern "C" void kernel_launch(void* const* d_in, const int* in_sizes, int n_in,
                              void* d_out, int out_size, void* d_ws, size_t ws_size,
                              hipStream_t stream) {
  const float* x      = (const float*)d_in[0];
  const int*   mask   = (const int*)  d_in[1];
  const int*   labels = (const int*)  d_in[2];
  const float* W      = (const float*)d_in[3];
  const float* bias   = (const float*)d_in[4];
  const float* trans  = (const float*)d_in[5];
  const float* startv = (const float*)d_in[6];
  const float* endv   = (const float*)d_in[7];

  float* out  = (float*)d_out;
  float* feat = out;                 // output 0: features [B][S][T]
  float* pred = out + PRED_OFF;      // output 1: pred_labels as float [B][S]
  float* loss = out + LOSS_OFF;      // output 2: scalar loss
  float* wsLogZ = (float*)d_ws;
  float* wsGold = wsLogZ + 64;

  gemm_feat<<<(Bn*Sn)/64, 256, 0, stream>>>(x, W, bias, feat);
  crf_kernel<<<192, 64, 0, stream>>>(feat, mask, labels, trans, startv, endv, pred, wsLogZ, wsGold);
  loss_reduce<<<1, 64, 0, stream>>>(wsLogZ, wsGold, loss);
}

// Round 5
// 349.850 us; speedup vs baseline: 1.2348x; 1.0179x over previous
//
#include <hip/hip_runtime.h>
#include <hip/hip_bf16.h>
#include <math.h>

#define Bn 64
#define Sn 512
#define Hn 1024
#define Tn 48

#define LOG2E 1.4426950408889634f
#define LN2f  0.6931471805599453f

#define PRED_OFF (Bn*Sn*Tn)
#define LOSS_OFF (PRED_OFF + Bn*Sn)

#define RL(x,i) __int_as_float(__builtin_amdgcn_readlane(__float_as_int(x),(i)))

#if __has_builtin(__builtin_amdgcn_exp2f)
#define EXP2(x) __builtin_amdgcn_exp2f(x)
#else
#define EXP2(x) exp2f(x)
#endif
#if __has_builtin(__builtin_amdgcn_logf)
#define LOG2(x) __builtin_amdgcn_logf(x)
#else
#define LOG2(x) log2f(x)
#endif

__device__ __forceinline__ int imin(int a, int b) { return a < b ? a : b; }

// ======================= GEMM: feat = x @ W + b =======================
// BM=64, BN=48, BK=64. 128 threads; per-thread 4 rows x 6 cols.
// x tile in LDS as [kk4][row + row/4] float4 -> conflict-free 4-row reads.
__global__ __launch_bounds__(128) void gemm_feat(
    const float* __restrict__ x, const float* __restrict__ W,
    const float* __restrict__ bias, float* __restrict__ feat)
{
  __shared__ __align__(16) float4 xs2[16][80];   // [kk4][row'] row' = row + row/4
  __shared__ __align__(16) float wsT[Tn][68];
  const int tid = threadIdx.x;
  const int tx = tid & 7;          // col group: cols tx*6 .. tx*6+5
  const int ty = tid >> 3;         // 0..15 -> rows ty*4 .. ty*4+3
  const size_t row0 = (size_t)blockIdx.x * 64;
  const int srow  = tid >> 1;      // 0..63 staging row
  const int shalf = tid & 1;       // which 8-kk4 half
  const int srowp = srow + (srow >> 2);

  float4 xreg[8];
  float  wreg[24];
  #pragma unroll
  for (int p = 0; p < 8; ++p)
    xreg[p] = *reinterpret_cast<const float4*>(&x[(row0 + srow)*Hn + (shalf*8 + p)*4]);
  #pragma unroll
  for (int i = 0; i < 24; ++i) {
    const int id = tid + i*128; const int kk = id/Tn; const int t = id - kk*Tn;
    wreg[i] = W[(size_t)kk*Tn + t];
  }

  float acc[4][6];
  #pragma unroll
  for (int r = 0; r < 4; ++r)
    #pragma unroll
    for (int c = 0; c < 6; ++c) acc[r][c] = 0.f;

  for (int k0 = 0; k0 < Hn; k0 += 64) {
    #pragma unroll
    for (int p = 0; p < 8; ++p)
      xs2[shalf*8 + p][srowp] = xreg[p];
    #pragma unroll
    for (int i = 0; i < 24; ++i) {
      const int id = tid + i*128; const int kk = id/Tn; const int t = id - kk*Tn;
      wsT[t][kk] = wreg[i];
    }
    __syncthreads();
    if (k0 + 64 < Hn) {
      #pragma unroll
      for (int p = 0; p < 8; ++p)
        xreg[p] = *reinterpret_cast<const float4*>(&x[(row0 + srow)*Hn + (k0+64) + (shalf*8 + p)*4]);
      #pragma unroll
      for (int i = 0; i < 24; ++i) {
        const int id = tid + i*128; const int kk = id/Tn; const int t = id - kk*Tn;
        wreg[i] = W[(size_t)(k0 + 64 + kk)*Tn + t];
      }
    }
    #pragma unroll
    for (int kk4 = 0; kk4 < 16; ++kk4) {
      const float4 a0 = xs2[kk4][5*ty + 0];
      const float4 a1 = xs2[kk4][5*ty + 1];
      const float4 a2 = xs2[kk4][5*ty + 2];
      const float4 a3 = xs2[kk4][5*ty + 3];
      const float4 w0 = *reinterpret_cast<const float4*>(&wsT[tx*6+0][kk4*4]);
      const float4 w1 = *reinterpret_cast<const float4*>(&wsT[tx*6+1][kk4*4]);
      const float4 w2 = *reinterpret_cast<const float4*>(&wsT[tx*6+2][kk4*4]);
      const float4 w3 = *reinterpret_cast<const float4*>(&wsT[tx*6+3][kk4*4]);
      const float4 w4 = *reinterpret_cast<const float4*>(&wsT[tx*6+4][kk4*4]);
      const float4 w5 = *reinterpret_cast<const float4*>(&wsT[tx*6+5][kk4*4]);
      #define FMA4(ACC,A,B) { ACC = fmaf((A).x,(B).x,ACC); ACC = fmaf((A).y,(B).y,ACC); ACC = fmaf((A).z,(B).z,ACC); ACC = fmaf((A).w,(B).w,ACC); }
      FMA4(acc[0][0],a0,w0) FMA4(acc[0][1],a0,w1) FMA4(acc[0][2],a0,w2)
      FMA4(acc[0][3],a0,w3) FMA4(acc[0][4],a0,w4) FMA4(acc[0][5],a0,w5)
      FMA4(acc[1][0],a1,w0) FMA4(acc[1][1],a1,w1) FMA4(acc[1][2],a1,w2)
      FMA4(acc[1][3],a1,w3) FMA4(acc[1][4],a1,w4) FMA4(acc[1][5],a1,w5)
      FMA4(acc[2][0],a2,w0) FMA4(acc[2][1],a2,w1) FMA4(acc[2][2],a2,w2)
      FMA4(acc[2][3],a2,w3) FMA4(acc[2][4],a2,w4) FMA4(acc[2][5],a2,w5)
      FMA4(acc[3][0],a3,w0) FMA4(acc[3][1],a3,w1) FMA4(acc[3][2],a3,w2)
      FMA4(acc[3][3],a3,w3) FMA4(acc[3][4],a3,w4) FMA4(acc[3][5],a3,w5)
      #undef FMA4
    }
    __syncthreads();
  }
  #pragma unroll
  for (int c = 0; c < 6; ++c) {
    const int col = tx*6 + c;
    const float bv = bias[col];
    #pragma unroll
    for (int r = 0; r < 4; ++r)
      feat[(row0 + ty*4 + r)*Tn + col] = acc[r][c] + bv;
  }
}

// ======================= CRF: 192 single-wave blocks =======================
// role 0: log-partition (linear-space matvec, log2 rebased)
// role 1: Viterbi forward (max3 value tree + equality/min-tree index, all
//         log-depth; index off the critical path) + segment-parallel backtrace
// role 2: gold score
__global__ __launch_bounds__(64, 1) void crf_kernel(
    const float* __restrict__ feat,
    const int* __restrict__ mask,
    const int* __restrict__ labels,
    const float* __restrict__ trans,
    const float* __restrict__ startv,
    const float* __restrict__ endv,
    float* __restrict__ pred_out,
    float* __restrict__ wsLogZ,
    float* __restrict__ wsGold)
{
  __shared__ unsigned char bpL[Sn * 64];     // 32 KB backpointers, stride 64
  __shared__ unsigned char pathL[384 * 64];  // 24 KB segment paths
  __shared__ int EA[8];

  const int role = blockIdx.x >> 6;
  const int b    = blockIdx.x & 63;
  const int lane = threadIdx.x;
  const float* fb = feat + (size_t)b * Sn * Tn;

  // sequence length (mask is a prefix mask)
  int lc = 0;
  #pragma unroll
  for (int it = 0; it < Sn/64; ++it) lc += (mask[(size_t)b*Sn + it*64 + lane] != 0);
  #pragma unroll
  for (int off = 32; off; off >>= 1) lc += __shfl_xor(lc, off);
  const int len = lc;

  const int j = (lane < Tn) ? lane : (Tn - 1);

  if (role == 0) {
    // ---------------- log-partition ----------------
    float Ev[48];
    #pragma unroll
    for (int i = 0; i < 48; ++i) Ev[i] = EXP2(trans[i*Tn + j] * LOG2E); // e^trans
    const float a0 = (startv[j] + fb[j]) * LOG2E;
    float Zref = RL(a0, 0);
    float beta = a0 - Zref;                  // beta[0] == 0
    float em2 = fb[Tn + j] * LOG2E;
    for (int t = 1; t < len; ++t) {
      const int tn = (t + 1 < len) ? (t + 1) : t;
      const float em_nxt = fb[(size_t)tn*Tn + j] * LOG2E;
      const float p = EXP2(beta);
      float s0=0.f, s1=0.f, s2=0.f, s3=0.f;
      #pragma unroll
      for (int i = 0; i < 48; i += 4) {
        s0 = fmaf(RL(p, i+0), Ev[i+0], s0);
        s1 = fmaf(RL(p, i+1), Ev[i+1], s1);
        s2 = fmaf(RL(p, i+2), Ev[i+2], s2);
        s3 = fmaf(RL(p, i+3), Ev[i+3], s3);
      }
      const float dj = LOG2((s0 + s1) + (s2 + s3)) + em2;
      const float d0 = RL(dj, 0);
      Zref += d0;
      beta = dj - d0;
      em2 = em_nxt;
    }
    float fv = (lane < Tn) ? beta + endv[lane] * LOG2E : -INFINITY;
    float m = fv;
    #pragma unroll
    for (int off = 32; off; off >>= 1) m = fmaxf(m, __shfl_xor(m, off));
    float e = (lane < Tn) ? EXP2(fv - m) : 0.f;
    #pragma unroll
    for (int off = 32; off; off >>= 1) e += __shfl_xor(e, off);
    if (lane == 0) wsLogZ[b] = (Zref + m + LOG2(e)) * LN2f;

  } else if (role == 1) {
    // ---------------- Viterbi forward ----------------
    float trv[48];
    #pragma unroll
    for (int i = 0; i < 48; ++i) trv[i] = trans[i*Tn + j];
    float v = startv[j] + fb[j];
    float em_cur = fb[Tn + j];
    for (int t = 1; t < len; ++t) {
      const int tn = (t + 1 < len) ? (t + 1) : t;
      const float em_nxt = fb[(size_t)tn*Tn + j];
      float q[48];
      #pragma unroll
      for (int i = 0; i < 48; ++i) q[i] = RL(v, i) + trv[i];
      // value: max3 tree (log depth, no index carried)
      float m16[16];
      #pragma unroll
      for (int u = 0; u < 16; ++u)
        m16[u] = fmaxf(fmaxf(q[3*u], q[3*u+1]), q[3*u+2]);
      float m6a = fmaxf(fmaxf(m16[0],  m16[1]),  m16[2]);
      float m6b = fmaxf(fmaxf(m16[3],  m16[4]),  m16[5]);
      float m6c = fmaxf(fmaxf(m16[6],  m16[7]),  m16[8]);
      float m6d = fmaxf(fmaxf(m16[9],  m16[10]), m16[11]);
      float m6e = fmaxf(fmaxf(m16[12], m16[13]), m16[14]);
      float m6f = m16[15];
      const float best = fmaxf(fmaxf(fmaxf(m6a,m6b),m6c),
                               fmaxf(fmaxf(m6d,m6e),m6f));
      // index: exact equality select + min tree (off critical path)
      int s16[16];
      #pragma unroll
      for (int u = 0; u < 16; ++u) {
        int a = (q[3*u]   == best) ? (3*u)   : 63;
        int bq = (q[3*u+1] == best) ? (3*u+1) : 63;
        int cq = (q[3*u+2] == best) ? (3*u+2) : 63;
        s16[u] = imin(imin(a, bq), cq);
      }
      int i6a = imin(imin(s16[0],  s16[1]),  s16[2]);
      int i6b = imin(imin(s16[3],  s16[4]),  s16[5]);
      int i6c = imin(imin(s16[6],  s16[7]),  s16[8]);
      int i6d = imin(imin(s16[9],  s16[10]), s16[11]);
      int i6e = imin(imin(s16[12], s16[13]), s16[14]);
      int i6f = s16[15];
      const int bidx = imin(imin(imin(i6a,i6b),i6c), imin(imin(i6d,i6e),i6f));
      bpL[t*64 + lane] = (unsigned char)bidx;
      v = best + em_cur;
      em_cur = em_nxt;
    }
    // identity backpointers for masked steps
    for (int t = len; t < Sn; ++t) bpL[t*64 + lane] = (unsigned char)lane;

    // final first-occurrence argmax across lanes
    float fv = (lane < Tn) ? v + endv[lane] : -INFINITY;
    int fi = (lane < Tn) ? lane : 64;
    #pragma unroll
    for (int off = 32; off; off >>= 1) {
      const float ov = __shfl_xor(fv, off);
      const int   oi = __shfl_xor(fi, off);
      if (ov > fv || (ov == fv && oi < fi)) { fv = ov; fi = oi; }
    }
    __syncthreads();

    // ---- segment-parallel backtrace: 8 segments x 48 entry tags = 384 jobs,
    //      6 interleaved chains per lane ----
    #define JOB(r) \
      const int id##r  = lane + 64*(r); \
      const int seg##r = id##r & 7;     \
      int cur##r = id##r >> 3;          \
      const int bpb##r = seg##r << 12;  \
      const int pb##r  = id##r << 6;    \
      pathL[pb##r + 63] = (unsigned char)cur##r;
    JOB(0) JOB(1) JOB(2) JOB(3) JOB(4) JOB(5)
    for (int d = 62; d >= 0; --d) {
      const int o = (d + 1) << 6;
      cur0 = bpL[bpb0 + o + cur0]; pathL[pb0 + d] = (unsigned char)cur0;
      cur1 = bpL[bpb1 + o + cur1]; pathL[pb1 + d] = (unsigned char)cur1;
      cur2 = bpL[bpb2 + o + cur2]; pathL[pb2 + d] = (unsigned char)cur2;
      cur3 = bpL[bpb3 + o + cur3]; pathL[pb3 + d] = (unsigned char)cur3;
      cur4 = bpL[bpb4 + o + cur4]; pathL[pb4 + d] = (unsigned char)cur4;
      cur5 = bpL[bpb5 + o + cur5]; pathL[pb5 + d] = (unsigned char)cur5;
    }
    #undef JOB
    __syncthreads();
    // stitch: E[s] = tag at position 64s+63
    if (lane == 0) {
      int Ecur = fi;                       // tag at 511 (identity-propagated)
      EA[7] = Ecur;
      for (int s = 7; s >= 1; --s) {
        const int bottom = pathL[((Ecur << 3) + s) * 64];   // tag at 64s
        Ecur = bpL[(s << 12) + bottom];                     // bp[64s][.] -> tag at 64s-1
        EA[s-1] = Ecur;
      }
    }
    __syncthreads();
    #pragma unroll
    for (int r8 = 0; r8 < 8; ++r8) {
      const int t = r8*64 + lane;
      const int pv = pathL[((EA[r8] << 3) + r8) * 64 + lane];
      pred_out[(size_t)b*Sn + t] = (t < len) ? (float)pv : 0.f;
    }

  } else {
    // ---------------- gold score ----------------
    float g = 0.f;
    #pragma unroll
    for (int it = 0; it < Sn/64; ++it) {
      const int sg = it*64 + lane;
      if (sg < len) {
        const int la = labels[(size_t)b*Sn + sg];
        float e = fb[(size_t)sg*Tn + la];
        if (sg > 0) e += trans[labels[(size_t)b*Sn + sg - 1]*Tn + la];
        g += e;
      }
    }
    #pragma unroll
    for (int off = 32; off; off >>= 1) g += __shfl_xor(g, off);
    if (lane == 0) {
      g += startv[labels[(size_t)b*Sn]] + endv[labels[(size_t)b*Sn + len - 1]];
      wsGold[b] = g;
    }
  }
}

__global__ void loss_reduce(const float* __restrict__ wsLogZ,
                            const float* __restrict__ wsGold,
                            float* __restrict__ out)
{
  const int lane = threadIdx.x;
  float v = wsLogZ[lane] - wsGold[lane];
  #pragma unroll
  for (int off = 32; off; off >>= 1) v += __shfl_xor(v, off);
  if (lane == 0) out[0] = v;
}

extern "C" void kernel_launch(void* const* d_in, const int* in_sizes, int n_in,
                              void* d_out, int out_size, void* d_ws, size_t ws_size,
                              hipStream_t stream) {
  const float* x      = (const float*)d_in[0];
  const int*   mask   = (const int*)  d_in[1];
  const int*   labels = (const int*)  d_in[2];
  const float* W      = (const float*)d_in[3];
  const float* bias   = (const float*)d_in[4];
  const float* trans  = (const float*)d_in[5];
  const float* startv = (const float*)d_in[6];
  const float* endv   = (const float*)d_in[7];

  float* out  = (float*)d_out;
  float* feat = out;                 // output 0: features [B][S][T]
  float* pred = out + PRED_OFF;      // output 1: pred_labels as float [B][S]
  float* loss = out + LOSS_OFF;      // output 2: scalar loss
  float* wsLogZ = (float*)d_ws;
  float* wsGold = wsLogZ + 64;

  gemm_feat<<<(Bn*Sn)/64, 128, 0, stream>>>(x, W, bias, feat);
  crf_kernel<<<192, 64, 0, stream>>>(feat, mask, labels, trans, startv, endv, pred, wsLogZ, wsGold);
  loss_reduce<<<1, 64, 0, stream>>>(wsLogZ, wsGold, loss);
}

// Round 6
// 323.896 us; speedup vs baseline: 1.3338x; 1.0801x over previous
//
#include <hip/hip_runtime.h>
#include <hip/hip_bf16.h>
#include <math.h>

#define Bn 64
#define Sn 512
#define Hn 1024
#define Tn 48

#define LOG2E 1.4426950408889634f
#define LN2f  0.6931471805599453f

#define PRED_OFF (Bn*Sn*Tn)
#define LOSS_OFF (PRED_OFF + Bn*Sn)

#define RL(x,i) __int_as_float(__builtin_amdgcn_readlane(__float_as_int(x),(i)))

#if __has_builtin(__builtin_amdgcn_exp2f)
#define EXP2(x) __builtin_amdgcn_exp2f(x)
#else
#define EXP2(x) exp2f(x)
#endif
#if __has_builtin(__builtin_amdgcn_logf)
#define LOG2(x) __builtin_amdgcn_logf(x)
#else
#define LOG2(x) log2f(x)
#endif

__device__ __forceinline__ unsigned umin2(unsigned a, unsigned b) { return a < b ? a : b; }

// ======================= GEMM: feat = x @ W + b =======================
// R4 config (measured best): BM=64, 256 threads, per-thread 2 rows x 6 cols.
// Register-prefetch double staging. a-reads 2-way (free), w-reads broadcast.
#define DOT4(ACC,A,B) { ACC = fmaf((A).x,(B).x,ACC); ACC = fmaf((A).y,(B).y,ACC); ACC = fmaf((A).z,(B).z,ACC); ACC = fmaf((A).w,(B).w,ACC); }

__global__ __launch_bounds__(256) void gemm_feat(
    const float* __restrict__ x, const float* __restrict__ W,
    const float* __restrict__ bias, float* __restrict__ feat)
{
  __shared__ __align__(16) float xs[64][68];
  __shared__ __align__(16) float wsT[Tn][68];
  const int tid = threadIdx.x;
  const int srow = tid >> 2;        // 0..63 staging row
  const int sqc  = tid & 3;         // 0..3  staging quad-col base
  const int ty = tid >> 3;          // 0..31 -> rows ty*2, ty*2+1
  const int tx = tid & 7;           // 0..7  -> cols tx*6 .. tx*6+5
  const size_t row0 = (size_t)blockIdx.x * 64;

  float4 xreg[4];
  float  wreg[12];
  #pragma unroll
  for (int p = 0; p < 4; ++p)
    xreg[p] = *reinterpret_cast<const float4*>(&x[(row0 + srow)*Hn + (sqc + p*4)*4]);
  #pragma unroll
  for (int i = 0; i < 12; ++i) {
    const int id = tid + i*256; const int kk = id/Tn; const int t = id - kk*Tn;
    wreg[i] = W[(size_t)kk*Tn + t];
  }

  float acc[2][6];
  #pragma unroll
  for (int r = 0; r < 2; ++r)
    #pragma unroll
    for (int c = 0; c < 6; ++c) acc[r][c] = 0.f;

  for (int k0 = 0; k0 < Hn; k0 += 64) {
    #pragma unroll
    for (int p = 0; p < 4; ++p)
      *reinterpret_cast<float4*>(&xs[srow][(sqc + p*4)*4]) = xreg[p];
    #pragma unroll
    for (int i = 0; i < 12; ++i) {
      const int id = tid + i*256; const int kk = id/Tn; const int t = id - kk*Tn;
      wsT[t][kk] = wreg[i];
    }
    __syncthreads();
    if (k0 + 64 < Hn) {
      #pragma unroll
      for (int p = 0; p < 4; ++p)
        xreg[p] = *reinterpret_cast<const float4*>(&x[(row0 + srow)*Hn + (k0+64) + (sqc + p*4)*4]);
      #pragma unroll
      for (int i = 0; i < 12; ++i) {
        const int id = tid + i*256; const int kk = id/Tn; const int t = id - kk*Tn;
        wreg[i] = W[(size_t)(k0 + 64 + kk)*Tn + t];
      }
    }
    #pragma unroll 4
    for (int kk = 0; kk < 64; kk += 4) {
      const float4 a0 = *reinterpret_cast<const float4*>(&xs[ty*2+0][kk]);
      const float4 a1 = *reinterpret_cast<const float4*>(&xs[ty*2+1][kk]);
      const float4 w0 = *reinterpret_cast<const float4*>(&wsT[tx*6+0][kk]);
      const float4 w1 = *reinterpret_cast<const float4*>(&wsT[tx*6+1][kk]);
      const float4 w2 = *reinterpret_cast<const float4*>(&wsT[tx*6+2][kk]);
      const float4 w3 = *reinterpret_cast<const float4*>(&wsT[tx*6+3][kk]);
      const float4 w4 = *reinterpret_cast<const float4*>(&wsT[tx*6+4][kk]);
      const float4 w5 = *reinterpret_cast<const float4*>(&wsT[tx*6+5][kk]);
      DOT4(acc[0][0],a0,w0) DOT4(acc[0][1],a0,w1) DOT4(acc[0][2],a0,w2)
      DOT4(acc[0][3],a0,w3) DOT4(acc[0][4],a0,w4) DOT4(acc[0][5],a0,w5)
      DOT4(acc[1][0],a1,w0) DOT4(acc[1][1],a1,w1) DOT4(acc[1][2],a1,w2)
      DOT4(acc[1][3],a1,w3) DOT4(acc[1][4],a1,w4) DOT4(acc[1][5],a1,w5)
    }
    __syncthreads();
  }
  #pragma unroll
  for (int c = 0; c < 6; ++c) {
    const int col = tx*6 + c;
    const float bv = bias[col];
    #pragma unroll
    for (int r = 0; r < 2; ++r)
      feat[(row0 + ty*2 + r)*Tn + col] = acc[r][c] + bv;
  }
}

// ======================= CRF: 192 single-wave blocks =======================
// role 0: log-partition (linear-space matvec, LDS-broadcast p, log2 rebased)
// role 1: Viterbi forward (LDS-broadcast v; flag-free argmax via sign-bit key
//         + min_u32 tree) + segment-parallel backtrace
// role 2: gold score
__global__ __launch_bounds__(64, 1) void crf_kernel(
    const float* __restrict__ feat,
    const int* __restrict__ mask,
    const int* __restrict__ labels,
    const float* __restrict__ trans,
    const float* __restrict__ startv,
    const float* __restrict__ endv,
    float* __restrict__ pred_out,
    float* __restrict__ wsLogZ,
    float* __restrict__ wsGold)
{
  __shared__ unsigned char bpL[Sn * 64];     // 32 KB backpointers, stride 64
  __shared__ unsigned char pathL[384 * 64];  // 24 KB segment paths
  __shared__ __align__(16) float slds[64];   // state broadcast buffer
  __shared__ int EA[8];

  const int role = blockIdx.x >> 6;
  const int b    = blockIdx.x & 63;
  const int lane = threadIdx.x;
  const float* fb = feat + (size_t)b * Sn * Tn;

  // sequence length (mask is a prefix mask)
  int lc = 0;
  #pragma unroll
  for (int it = 0; it < Sn/64; ++it) lc += (mask[(size_t)b*Sn + it*64 + lane] != 0);
  #pragma unroll
  for (int off = 32; off; off >>= 1) lc += __shfl_xor(lc, off);
  const int len = lc;

  const int j = (lane < Tn) ? lane : (Tn - 1);
  const float4* sv4 = reinterpret_cast<const float4*>(slds);

  if (role == 0) {
    // ---------------- log-partition ----------------
    float Ev[48];
    #pragma unroll
    for (int i = 0; i < 48; ++i) Ev[i] = EXP2(trans[i*Tn + j] * LOG2E); // e^trans
    const float a0 = (startv[j] + fb[j]) * LOG2E;
    float Zref = RL(a0, 0);
    float beta = a0 - Zref;                  // beta[0] == 0
    slds[lane] = EXP2(beta);
    float em2 = fb[Tn + j] * LOG2E;
    for (int t = 1; t < len; ++t) {
      const int tn = (t + 1 < len) ? (t + 1) : t;
      const float em_nxt = fb[(size_t)tn*Tn + j] * LOG2E;
      float4 av[12];
      #pragma unroll
      for (int k = 0; k < 12; ++k) av[k] = sv4[k];   // broadcast reads
      float s0=0.f, s1=0.f, s2=0.f, s3=0.f;
      #pragma unroll
      for (int k = 0; k < 12; ++k) {
        s0 = fmaf(av[k].x, Ev[4*k+0], s0);
        s1 = fmaf(av[k].y, Ev[4*k+1], s1);
        s2 = fmaf(av[k].z, Ev[4*k+2], s2);
        s3 = fmaf(av[k].w, Ev[4*k+3], s3);
      }
      const float dj = LOG2((s0 + s1) + (s2 + s3)) + em2;
      const float d0 = RL(dj, 0);
      Zref += d0;
      const float nb = dj - d0;
      slds[lane] = EXP2(nb);                 // write after reads: in-wave order
      beta = nb;
      em2 = em_nxt;
    }
    float fv = (lane < Tn) ? beta + endv[lane] * LOG2E : -INFINITY;
    float m = fv;
    #pragma unroll
    for (int off = 32; off; off >>= 1) m = fmaxf(m, __shfl_xor(m, off));
    float e = (lane < Tn) ? EXP2(fv - m) : 0.f;
    #pragma unroll
    for (int off = 32; off; off >>= 1) e += __shfl_xor(e, off);
    if (lane == 0) wsLogZ[b] = (Zref + m + LOG2(e)) * LN2f;

  } else if (role == 1) {
    // ---------------- Viterbi forward ----------------
    float trv[48];
    #pragma unroll
    for (int i = 0; i < 48; ++i) trv[i] = trans[i*Tn + j];
    float v = startv[j] + fb[j];
    slds[lane] = v;
    float em_cur = fb[Tn + j];
    for (int t = 1; t < len; ++t) {
      const int tn = (t + 1 < len) ? (t + 1) : t;
      const float em_nxt = fb[(size_t)tn*Tn + j];
      float4 av[12];
      #pragma unroll
      for (int k = 0; k < 12; ++k) av[k] = sv4[k];   // broadcast reads
      float q[48];
      #pragma unroll
      for (int k = 0; k < 12; ++k) {
        q[4*k+0] = av[k].x + trv[4*k+0];
        q[4*k+1] = av[k].y + trv[4*k+1];
        q[4*k+2] = av[k].z + trv[4*k+2];
        q[4*k+3] = av[k].w + trv[4*k+3];
      }
      // value: max3 tree (flag-free)
      float m16[16];
      #pragma unroll
      for (int u = 0; u < 16; ++u)
        m16[u] = fmaxf(fmaxf(q[3*u], q[3*u+1]), q[3*u+2]);
      float m6a = fmaxf(fmaxf(m16[0],  m16[1]),  m16[2]);
      float m6b = fmaxf(fmaxf(m16[3],  m16[4]),  m16[5]);
      float m6c = fmaxf(fmaxf(m16[6],  m16[7]),  m16[8]);
      float m6d = fmaxf(fmaxf(m16[9],  m16[10]), m16[11]);
      float m6e = fmaxf(fmaxf(m16[12], m16[13]), m16[14]);
      float m6f = m16[15];
      const float best = fmaxf(fmaxf(fmaxf(m6a,m6b),m6c),
                               fmaxf(fmaxf(m6d,m6e),m6f));
      // index: key = bits(q - best) | i ; ties -> key=i, others have sign bit.
      // min_u32 tree -> exact first-occurrence argmax, no flag ops.
      unsigned s16[16];
      #pragma unroll
      for (int u = 0; u < 16; ++u) {
        const unsigned ka = __float_as_uint(q[3*u]   - best) | (unsigned)(3*u);
        const unsigned kb = __float_as_uint(q[3*u+1] - best) | (unsigned)(3*u+1);
        const unsigned kc = __float_as_uint(q[3*u+2] - best) | (unsigned)(3*u+2);
        s16[u] = umin2(umin2(ka, kb), kc);
      }
      unsigned i6a = umin2(umin2(s16[0],  s16[1]),  s16[2]);
      unsigned i6b = umin2(umin2(s16[3],  s16[4]),  s16[5]);
      unsigned i6c = umin2(umin2(s16[6],  s16[7]),  s16[8]);
      unsigned i6d = umin2(umin2(s16[9],  s16[10]), s16[11]);
      unsigned i6e = umin2(umin2(s16[12], s16[13]), s16[14]);
      unsigned i6f = s16[15];
      const unsigned bidx = umin2(umin2(umin2(i6a,i6b),i6c), umin2(umin2(i6d,i6e),i6f));
      bpL[t*64 + lane] = (unsigned char)bidx;
      v = best + em_cur;
      slds[lane] = v;                        // write after reads: in-wave order
      em_cur = em_nxt;
    }
    // identity backpointers for masked steps
    for (int t = len; t < Sn; ++t) bpL[t*64 + lane] = (unsigned char)lane;

    // final first-occurrence argmax across lanes
    float fv = (lane < Tn) ? v + endv[lane] : -INFINITY;
    int fi = (lane < Tn) ? lane : 64;
    #pragma unroll
    for (int off = 32; off; off >>= 1) {
      const float ov = __shfl_xor(fv, off);
      const int   oi = __shfl_xor(fi, off);
      if (ov > fv || (ov == fv && oi < fi)) { fv = ov; fi = oi; }
    }
    __syncthreads();

    // ---- segment-parallel backtrace: 8 segments x 48 entry tags = 384 jobs,
    //      6 interleaved chains per lane ----
    #define JOB(r) \
      const int id##r  = lane + 64*(r); \
      const int seg##r = id##r & 7;     \
      int cur##r = id##r >> 3;          \
      const int bpb##r = seg##r << 12;  \
      const int pb##r  = id##r << 6;    \
      pathL[pb##r + 63] = (unsigned char)cur##r;
    JOB(0) JOB(1) JOB(2) JOB(3) JOB(4) JOB(5)
    for (int d = 62; d >= 0; --d) {
      const int o = (d + 1) << 6;
      cur0 = bpL[bpb0 + o + cur0]; pathL[pb0 + d] = (unsigned char)cur0;
      cur1 = bpL[bpb1 + o + cur1]; pathL[pb1 + d] = (unsigned char)cur1;
      cur2 = bpL[bpb2 + o + cur2]; pathL[pb2 + d] = (unsigned char)cur2;
      cur3 = bpL[bpb3 + o + cur3]; pathL[pb3 + d] = (unsigned char)cur3;
      cur4 = bpL[bpb4 + o + cur4]; pathL[pb4 + d] = (unsigned char)cur4;
      cur5 = bpL[bpb5 + o + cur5]; pathL[pb5 + d] = (unsigned char)cur5;
    }
    #undef JOB
    __syncthreads();
    // stitch: E[s] = tag at position 64s+63
    if (lane == 0) {
      int Ecur = fi;                       // tag at 511 (identity-propagated)
      EA[7] = Ecur;
      for (int s = 7; s >= 1; --s) {
        const int bottom = pathL[((Ecur << 3) + s) * 64];   // tag at 64s
        Ecur = bpL[(s << 12) + bottom];                     // bp[64s][.] -> tag at 64s-1
        EA[s-1] = Ecur;
      }
    }
    __syncthreads();
    #pragma unroll
    for (int r8 = 0; r8 < 8; ++r8) {
      const int t = r8*64 + lane;
      const int pv = pathL[((EA[r8] << 3) + r8) * 64 + lane];
      pred_out[(size_t)b*Sn + t] = (t < len) ? (float)pv : 0.f;
    }

  } else {
    // ---------------- gold score ----------------
    float g = 0.f;
    #pragma unroll
    for (int it = 0; it < Sn/64; ++it) {
      const int sg = it*64 + lane;
      if (sg < len) {
        const int la = labels[(size_t)b*Sn + sg];
        float e = fb[(size_t)sg*Tn + la];
        if (sg > 0) e += trans[labels[(size_t)b*Sn + sg - 1]*Tn + la];
        g += e;
      }
    }
    #pragma unroll
    for (int off = 32; off; off >>= 1) g += __shfl_xor(g, off);
    if (lane == 0) {
      g += startv[labels[(size_t)b*Sn]] + endv[labels[(size_t)b*Sn + len - 1]];
      wsGold[b] = g;
    }
  }
}

__global__ void loss_reduce(const float* __restrict__ wsLogZ,
                            const float* __restrict__ wsGold,
                            float* __restrict__ out)
{
  const int lane = threadIdx.x;
  float v = wsLogZ[lane] - wsGold[lane];
  #pragma unroll
  for (int off = 32; off; off >>= 1) v += __shfl_xor(v, off);
  if (lane == 0) out[0] = v;
}

extern "C" void kernel_launch(void* const* d_in, const int* in_sizes, int n_in,
                              void* d_out, int out_size, void* d_ws, size_t ws_size,
                              hipStream_t stream) {
  const float* x      = (const float*)d_in[0];
  const int*   mask   = (const int*)  d_in[1];
  const int*   labels = (const int*)  d_in[2];
  const float* W      = (const float*)d_in[3];
  const float* bias   = (const float*)d_in[4];
  const float* trans  = (const float*)d_in[5];
  const float* startv = (const float*)d_in[6];
  const float* endv   = (const float*)d_in[7];

  float* out  = (float*)d_out;
  float* feat = out;                 // output 0: features [B][S][T]
  float* pred = out + PRED_OFF;      // output 1: pred_labels as float [B][S]
  float* loss = out + LOSS_OFF;      // output 2: scalar loss
  float* wsLogZ = (float*)d_ws;
  float* wsGold = wsLogZ + 64;

  gemm_feat<<<(Bn*Sn)/64, 256, 0, stream>>>(x, W, bias, feat);
  crf_kernel<<<192, 64, 0, stream>>>(feat, mask, labels, trans, startv, endv, pred, wsLogZ, wsGold);
  loss_reduce<<<1, 64, 0, stream>>>(wsLogZ, wsGold, loss);
}